// Round 2
// baseline (3993.935 us; speedup 1.0000x reference)
//
#include <hip/hip_runtime.h>
#include <cstdint>
#include <cstddef>

#define T_OBS_C 64
#define T_UNOBS_C 32
#define BATCH_C 4096
#define HID_C 256

typedef short v8s __attribute__((ext_vector_type(8)));
typedef float v4f __attribute__((ext_vector_type(4)));
typedef unsigned short u16x8 __attribute__((ext_vector_type(8)));

__device__ __forceinline__ float bf2f(unsigned short u) {
  union { unsigned int i; float f; } v; v.i = ((unsigned int)u) << 16; return v.f;
}
__device__ __forceinline__ unsigned short f2bf(float f) {
  union { float f; unsigned int i; } v; v.f = f;
  unsigned int r = (v.i + 0x7FFFu + ((v.i >> 16) & 1u)) >> 16;
  return (unsigned short)r;
}

// ---------------------------------------------------------------------------
// prep:
//   Wc = wi @ stem_w2  (fp32, so gx_t = stem1_t @ Wc.T + bc_obs)  -> hi/lo bf16
//   wi, wh -> hi/lo bf16 splits
//   bc_obs[n] = sum_j wi[n][j]*b2[j] + bi[n]   (fp32)
// ---------------------------------------------------------------------------
__global__ void prep_kernel(const float* __restrict__ wi,
                            const float* __restrict__ w2,
                            const float* __restrict__ b2,
                            const float* __restrict__ bi,
                            unsigned short* __restrict__ wi_hi,
                            unsigned short* __restrict__ wi_lo,
                            const float* __restrict__ wh,
                            unsigned short* __restrict__ wh_hi,
                            unsigned short* __restrict__ wh_lo,
                            unsigned short* __restrict__ wc_hi,
                            unsigned short* __restrict__ wc_lo,
                            float* __restrict__ bc_obs) {
  const int n = blockIdx.x;     // 0..767
  const int k = threadIdx.x;    // 0..255
  const int idx = n * 256 + k;

  float wv = wi[idx];
  unsigned short h1 = f2bf(wv);
  wi_hi[idx] = h1; wi_lo[idx] = f2bf(wv - bf2f(h1));

  float hv = wh[idx];
  unsigned short h2 = f2bf(hv);
  wh_hi[idx] = h2; wh_lo[idx] = f2bf(hv - bf2f(h2));

  float acc = 0.f;
  for (int j = 0; j < 256; ++j)
    acc += wi[n * 256 + j] * w2[j * 256 + k];
  unsigned short h3 = f2bf(acc);
  wc_hi[idx] = h3; wc_lo[idx] = f2bf(acc - bf2f(h3));

  if (k == 0) {
    float b = 0.f;
    for (int j = 0; j < 256; ++j) b += wi[n * 256 + j] * b2[j];
    bc_obs[n] = b + bi[n];
  }
}

// ---------------------------------------------------------------------------
// One GRU step (obs or AR), fused GEMM + gate epilogue.
// Grid: (4 col-blocks of 64 gate-cols, 128 row-blocks of 32 batch rows).
// h kept as split bf16 (hi+lo); weights split bf16 (hi+lo); MFMA computes
// Whi*ah + Whi*al + Wlo*ah (residual Wlo*al ~1e-6, negligible).
// ---------------------------------------------------------------------------
__global__ __launch_bounds__(256, 2)
void step_kernel(const float* __restrict__ x_obs,
                 const float* __restrict__ t_obs,
                 const float* __restrict__ w1,
                 const float* __restrict__ b1,
                 const unsigned short* __restrict__ wi_hi,
                 const unsigned short* __restrict__ wi_lo,
                 const unsigned short* __restrict__ wh_hi,
                 const unsigned short* __restrict__ wh_lo,
                 const unsigned short* __restrict__ wc_hi,
                 const unsigned short* __restrict__ wc_lo,
                 const float* __restrict__ bc_obs,
                 const float* __restrict__ bi,
                 const float* __restrict__ bh,
                 const unsigned short* __restrict__ h_in_hi,
                 const unsigned short* __restrict__ h_in_lo,
                 unsigned short* __restrict__ h_out_hi,
                 unsigned short* __restrict__ h_out_lo,
                 float* __restrict__ out_z,
                 int is_obs, int t, int z_idx) {
  // 4 x 16KB = 64KB static LDS -> 2 WGs/CU
  __shared__ __align__(16) unsigned short lds_h_hi[8192];
  __shared__ __align__(16) unsigned short lds_h_lo[8192];
  __shared__ __align__(16) unsigned short lds_x_hi[8192];
  __shared__ __align__(16) unsigned short lds_x_lo[8192];

  const int tid = threadIdx.x;
  const int m0 = blockIdx.y * 32;   // batch-row block
  const int j0 = blockIdx.x * 64;   // gate-col block

  // ---- stage h (32 rows x 256 cols, hi+lo), XOR-swizzled per 8-elem chunk
  #pragma unroll
  for (int i = 0; i < 4; ++i) {
    int v = tid + i * 256;           // 0..1023 vec8 index
    int row = v >> 5;                // 32 vec8 per row
    int k8 = v & 31;
    size_t g = ((size_t)(m0 + row) << 8) + ((size_t)k8 << 3);
    u16x8 dhi = *(const u16x8*)(h_in_hi + g);
    u16x8 dlo = *(const u16x8*)(h_in_lo + g);
    int phys = (row << 8) + ((k8 ^ (row & 7)) << 3);
    *(u16x8*)(lds_h_hi + phys) = dhi;
    *(u16x8*)(lds_h_lo + phys) = dlo;
  }

  // ---- obs: stem1 = leaky_relu(xt @ w1.T + b1) computed exactly in fp32
  if (is_obs) {
    int bl = tid >> 3;               // 0..31 local row
    int kbase = (tid & 7) << 5;      // 8 threads cover 256 k in 32-chunks
    int b = m0 + bl;
    int xo = t * BATCH_C + b;
    float x0 = x_obs[(size_t)xo * 4 + 0];
    float x1 = x_obs[(size_t)xo * 4 + 1];
    float x2 = x_obs[(size_t)xo * 4 + 2];
    float x3 = x_obs[(size_t)xo * 4 + 3];
    float td = 0.f;
    if (t > 0) td = t_obs[xo] - t_obs[xo - BATCH_C];
    for (int j = 0; j < 32; ++j) {
      int k = kbase + j;
      const float* wr = w1 + k * 5;
      float pre = x0 * wr[0] + x1 * wr[1] + x2 * wr[2] +
                  x3 * wr[3] + td * wr[4] + b1[k];
      float a = (pre > 0.f) ? pre : 0.01f * pre;   // leaky_relu slope 0.01
      unsigned short hi = f2bf(a);
      unsigned short lo = f2bf(a - bf2f(hi));
      int phys = (bl << 8) + ((((k >> 3) ^ (bl & 7))) << 3) + (k & 7);
      lds_x_hi[phys] = hi;
      lds_x_lo[phys] = lo;
    }
  }
  __syncthreads();

  const int wave = tid >> 6;
  const int lane = tid & 63;
  const int quad = lane >> 4;
  const int l16 = lane & 15;
  const int jw = j0 + wave * 16;     // this wave's 16 gate-cols

  v4f acc[2][6];
  #pragma unroll
  for (int a = 0; a < 2; ++a)
    #pragma unroll
    for (int g = 0; g < 6; ++g)
      acc[a][g] = (v4f){0.f, 0.f, 0.f, 0.f};

  const unsigned short* Ah[2];
  const unsigned short* Al[2];
  const unsigned short* Bh[2];
  const unsigned short* Bl[2];
  Ah[0] = is_obs ? lds_x_hi : lds_h_hi;   // AR: x == h
  Al[0] = is_obs ? lds_x_lo : lds_h_lo;
  Bh[0] = is_obs ? wc_hi : wi_hi;         // [768,256] row-major = [n][k]
  Bl[0] = is_obs ? wc_lo : wi_lo;
  Ah[1] = lds_h_hi;
  Al[1] = lds_h_lo;
  Bh[1] = wh_hi;
  Bl[1] = wh_lo;

  #pragma unroll
  for (int s = 0; s < 2; ++s) {
    const unsigned short* ah_p = Ah[s];
    const unsigned short* al_p = Al[s];
    const unsigned short* bh_p = Bh[s];
    const unsigned short* bl_p = Bl[s];
    #pragma unroll
    for (int kc = 0; kc < 8; ++kc) {
      v8s bfh[3], bfl[3];
      #pragma unroll
      for (int g = 0; g < 3; ++g) {
        // B-frag: lane holds gate-row n, k = kc*32 + quad*8 .. +7 (contiguous)
        size_t bo = (((size_t)(g * 256 + jw + l16)) << 8) + kc * 32 + quad * 8;
        bfh[g] = *(const v8s*)(bh_p + bo);
        bfl[g] = *(const v8s*)(bl_p + bo);
      }
      #pragma unroll
      for (int mt = 0; mt < 2; ++mt) {
        int arow = mt * 16 + l16;    // A-frag: lane holds row m, k = quad*8..+7
        int chunk = (kc * 4 + quad) ^ (arow & 7);
        int aoff = (arow << 8) + (chunk << 3);
        v8s ahi = *(const v8s*)(ah_p + aoff);
        v8s alo = *(const v8s*)(al_p + aoff);
        #pragma unroll
        for (int g = 0; g < 3; ++g) {
          acc[mt][s * 3 + g] = __builtin_amdgcn_mfma_f32_16x16x32_bf16(
              ahi, bfh[g], acc[mt][s * 3 + g], 0, 0, 0);
          acc[mt][s * 3 + g] = __builtin_amdgcn_mfma_f32_16x16x32_bf16(
              alo, bfh[g], acc[mt][s * 3 + g], 0, 0, 0);
          acc[mt][s * 3 + g] = __builtin_amdgcn_mfma_f32_16x16x32_bf16(
              ahi, bfl[g], acc[mt][s * 3 + g], 0, 0, 0);
        }
      }
    }
  }

  // ---- gate epilogue: lane owns col jcol (C layout: col=lane&15, row=quad*4+reg)
  const int jcol = jw + l16;
  float xbr, xbz, xbn;
  if (is_obs) { xbr = bc_obs[jcol]; xbz = bc_obs[256 + jcol]; xbn = bc_obs[512 + jcol]; }
  else        { xbr = bi[jcol];     xbz = bi[256 + jcol];     xbn = bi[512 + jcol]; }
  float hbr = bh[jcol], hbz = bh[256 + jcol], hbn = bh[512 + jcol];

  #pragma unroll
  for (int mt = 0; mt < 2; ++mt) {
    #pragma unroll
    for (int rg = 0; rg < 4; ++rg) {
      int row_local = mt * 16 + quad * 4 + rg;
      float gr = acc[mt][0][rg] + xbr + acc[mt][3][rg] + hbr;
      float gz = acc[mt][1][rg] + xbz + acc[mt][4][rg] + hbz;
      float nx = acc[mt][2][rg] + xbn;
      float nh = acc[mt][5][rg] + hbn;
      float r = 1.f / (1.f + expf(-gr));
      float u = 1.f / (1.f + expf(-gz));
      float n = tanhf(nx + r * nh);
      int hp = (row_local << 8) + ((((jcol >> 3) ^ (row_local & 7))) << 3) + (jcol & 7);
      float hold = bf2f(lds_h_hi[hp]) + bf2f(lds_h_lo[hp]);
      float hnew = (1.f - u) * n + u * hold;
      unsigned short hi = f2bf(hnew);
      unsigned short lo = f2bf(hnew - bf2f(hi));
      size_t gi = ((size_t)(m0 + row_local) << 8) + jcol;
      h_out_hi[gi] = hi;
      h_out_lo[gi] = lo;
      if (z_idx >= 0) out_z[((size_t)z_idx << 20) + gi] = hnew;  // 4096*256 = 1<<20
    }
  }
}

// ---------------------------------------------------------------------------
// head: x_hats = zs @ head_w.T + head_b   (fp32 zs already in d_out)
// ---------------------------------------------------------------------------
__global__ void head_kernel(const float* __restrict__ zs,
                            const float* __restrict__ head_w,
                            const float* __restrict__ head_b,
                            float* __restrict__ out_x) {
  const int tid = threadIdx.x;
  const int row = blockIdx.x * 64 + (tid >> 2);     // 131072 rows total
  const int qk = (tid & 3) << 6;                    // 4 threads per row, 64 k each
  const float* zr = zs + ((size_t)row << 8) + qk;
  float a0 = 0.f, a1 = 0.f, a2 = 0.f, a3 = 0.f;
  for (int i = 0; i < 64; i += 4) {
    float4 z4 = *(const float4*)(zr + i);
    #pragma unroll
    for (int j = 0; j < 4; ++j) {
      float z = (j == 0) ? z4.x : (j == 1) ? z4.y : (j == 2) ? z4.z : z4.w;
      int k = qk + i + j;
      a0 += z * head_w[k];
      a1 += z * head_w[256 + k];
      a2 += z * head_w[512 + k];
      a3 += z * head_w[768 + k];
    }
  }
  a0 += __shfl_xor(a0, 1); a0 += __shfl_xor(a0, 2);
  a1 += __shfl_xor(a1, 1); a1 += __shfl_xor(a1, 2);
  a2 += __shfl_xor(a2, 1); a2 += __shfl_xor(a2, 2);
  a3 += __shfl_xor(a3, 1); a3 += __shfl_xor(a3, 2);
  if ((tid & 3) == 0) {
    size_t o = (size_t)row * 4;
    out_x[o + 0] = a0 + head_b[0];
    out_x[o + 1] = a1 + head_b[1];
    out_x[o + 2] = a2 + head_b[2];
    out_x[o + 3] = a3 + head_b[3];
  }
}

// ---------------------------------------------------------------------------
extern "C" void kernel_launch(void* const* d_in, const int* in_sizes, int n_in,
                              void* d_out, int out_size, void* d_ws, size_t ws_size,
                              hipStream_t stream) {
  const float* x_obs = (const float*)d_in[0];
  const float* t_obs = (const float*)d_in[1];
  // d_in[2] = t_unobs: only its length (32) matters
  const float* w1 = (const float*)d_in[3];
  const float* b1 = (const float*)d_in[4];
  const float* w2 = (const float*)d_in[5];
  const float* b2 = (const float*)d_in[6];
  const float* wi = (const float*)d_in[7];
  const float* wh = (const float*)d_in[8];
  const float* bi = (const float*)d_in[9];
  const float* bh = (const float*)d_in[10];
  const float* hw = (const float*)d_in[11];
  const float* hb = (const float*)d_in[12];

  float* out_x = (float*)d_out;                                  // [32,4096,4]
  float* out_z = out_x + (size_t)T_UNOBS_C * BATCH_C * 4;        // [32,4096,256]

  // workspace layout (~10.3 MB)
  unsigned short* p = (unsigned short*)d_ws;
  unsigned short* hA_hi = p; p += (1u << 20);
  unsigned short* hA_lo = p; p += (1u << 20);
  unsigned short* hB_hi = p; p += (1u << 20);
  unsigned short* hB_lo = p; p += (1u << 20);
  unsigned short* wi_hi = p; p += 768 * 256;
  unsigned short* wi_lo = p; p += 768 * 256;
  unsigned short* wh_hi = p; p += 768 * 256;
  unsigned short* wh_lo = p; p += 768 * 256;
  unsigned short* wc_hi = p; p += 768 * 256;
  unsigned short* wc_lo = p; p += 768 * 256;
  float* bc_obs = (float*)p;

  // h0 = 0 (hA pair is the step-0 input): 2 buffers x 2MB
  hipMemsetAsync(hA_hi, 0, (size_t)4 << 20, stream);

  prep_kernel<<<768, 256, 0, stream>>>(wi, w2, b2, bi,
                                       wi_hi, wi_lo, wh, wh_hi, wh_lo,
                                       wc_hi, wc_lo, bc_obs);

  dim3 grid(4, 128);
  int step = 0;
  for (int t = 0; t < T_OBS_C; ++t, ++step) {
    const unsigned short* ih = (step & 1) ? hB_hi : hA_hi;
    const unsigned short* il = (step & 1) ? hB_lo : hA_lo;
    unsigned short* oh = (step & 1) ? hA_hi : hB_hi;
    unsigned short* ol = (step & 1) ? hA_lo : hB_lo;
    step_kernel<<<grid, 256, 0, stream>>>(x_obs, t_obs, w1, b1,
                                          wi_hi, wi_lo, wh_hi, wh_lo, wc_hi, wc_lo,
                                          bc_obs, bi, bh,
                                          ih, il, oh, ol, out_z,
                                          1, t, (t == T_OBS_C - 1) ? 0 : -1);
  }
  for (int i = 0; i < T_UNOBS_C - 1; ++i, ++step) {
    const unsigned short* ih = (step & 1) ? hB_hi : hA_hi;
    const unsigned short* il = (step & 1) ? hB_lo : hA_lo;
    unsigned short* oh = (step & 1) ? hA_hi : hB_hi;
    unsigned short* ol = (step & 1) ? hA_lo : hB_lo;
    step_kernel<<<grid, 256, 0, stream>>>(x_obs, t_obs, w1, b1,
                                          wi_hi, wi_lo, wh_hi, wh_lo, wc_hi, wc_lo,
                                          bc_obs, bi, bh,
                                          ih, il, oh, ol, out_z,
                                          0, 0, i + 1);
  }
  head_kernel<<<(T_UNOBS_C * BATCH_C) / 64, 256, 0, stream>>>(out_z, hw, hb, out_x);
}